// Round 14
// baseline (299.587 us; speedup 1.0000x reference)
//
#include <hip/hip_runtime.h>
#include <math.h>

#define K 32
#define G 8
#define SIGMA_V 1.0f
#define RF __builtin_amdgcn_readfirstlane
#define REG 1024           // rows per region = per block (128 KB mu window)

// ws layout (floats): raw[G][K][K] @0 (8192), musum[G][K] @8192 (256), cnt[G] @8448
#define RAW_OFF   0
#define MUSUM_OFF 8192
#define CNT_OFF   8448
#define WS_FLOATS 8456

#define WAITV(n) asm volatile("s_waitcnt vmcnt(" #n ")" ::: "memory")
typedef __attribute__((address_space(3))) void lds_void;
typedef __attribute__((address_space(1))) void glb_void;
#define GLL(gsrc, ldst) __builtin_amdgcn_global_load_lds((const glb_void*)(gsrc), (lds_void*)(ldst), 16, 0, 0)

#define OUTER(a, b) { \
  acc[0]=fmaf(a.x,b.x,acc[0]);   acc[1]=fmaf(a.x,b.y,acc[1]);   acc[2]=fmaf(a.x,b.z,acc[2]);   acc[3]=fmaf(a.x,b.w,acc[3]); \
  acc[4]=fmaf(a.y,b.x,acc[4]);   acc[5]=fmaf(a.y,b.y,acc[5]);   acc[6]=fmaf(a.y,b.z,acc[6]);   acc[7]=fmaf(a.y,b.w,acc[7]); \
  acc[8]=fmaf(a.z,b.x,acc[8]);   acc[9]=fmaf(a.z,b.y,acc[9]);   acc[10]=fmaf(a.z,b.z,acc[10]); acc[11]=fmaf(a.z,b.w,acc[11]); \
  acc[12]=fmaf(a.w,b.x,acc[12]); acc[13]=fmaf(a.w,b.y,acc[13]); acc[14]=fmaf(a.w,b.z,acc[14]); acc[15]=fmaf(a.w,b.w,acc[15]); \
  ms[0]+=b.x; ms[1]+=b.y; ms[2]+=b.z; ms[3]+=b.w; }

// ---- fused: local LDS sort (pre-acc) + wave-per-group gather within 128KB window ----
// 512 thr = 8 waves; wave w owns group w. No branches in hot loop; no barrier after sort.
__global__ __launch_bounds__(512, 2) void gmm_all(const float* __restrict__ mu,
                                                  const int* __restrict__ lab,
                                                  float* __restrict__ ws) {
  __shared__ float stg[G][2][8][K];   // 16 KB: per-wave double-buffered 8-row stage
  __shared__ int sIdx[REG];           // 4 KB: locally-sorted row ids (0..1023)
  __shared__ int lcnt[G], lofs[G + 1], lpos[G];
  const int tid = threadIdx.x, wave = tid >> 6, lane = tid & 63;
  const int i8 = lane >> 3, j8 = lane & 7;   // compute: 8x8 lane grid, 4x4 tile/lane
  const int lg = lane >> 3, lf = lane & 7;   // staging mapping
  const long rbase = (long)blockIdx.x * REG;

  // ---- prologue sort (accumulators not yet live -> no cross-barrier reg pressure) ----
  if (tid < G) { lcnt[tid] = 0; lpos[tid] = 0; }
  __syncthreads();
  const int2 lv = *reinterpret_cast<const int2*>(lab + rbase + tid * 2);
  atomicAdd(&lcnt[lv.x], 1); atomicAdd(&lcnt[lv.y], 1);
  __syncthreads();
  if (tid == 0) {
    int o = 0;
    #pragma unroll
    for (int g2 = 0; g2 < G; ++g2) { lofs[g2] = o; o += lcnt[g2]; }
    lofs[G] = o;
  }
  __syncthreads();
  int p;
  p = atomicAdd(&lpos[lv.x], 1); sIdx[lofs[lv.x] + p] = tid * 2;
  p = atomicAdd(&lpos[lv.y], 1); sIdx[lofs[lv.y] + p] = tid * 2 + 1;
  __syncthreads();                            // sIdx ready; waves free-run from here

  // ---- wave-private consume: group g = wave ----
  const int g = wave;
  const int s0  = RF(lofs[g]);
  const int cnt = RF(lcnt[g]);                // ~128 +- 11
  float acc[16], ms[4];
  #pragma unroll
  for (int e = 0; e < 16; ++e) acc[e] = 0.f;
  ms[0] = ms[1] = ms[2] = ms[3] = 0.f;

  const int nch = cnt >> 3;                   // 8-row chunks
  if (nch > 0) {                              // 2-deep GLL pipeline; idx all from LDS
    {
      const int r = sIdx[s0 + lg];
      GLL(mu + (rbase + r) * K + lf * 4, &stg[wave][0][0][0]);
    }
    for (int k = 0; k < nch; ++k) {
      if (k + 1 < nch) {
        const int r = sIdx[s0 + (k + 1) * 8 + lg];
        GLL(mu + (rbase + r) * K + lf * 4, &stg[wave][(k + 1) & 1][0][0]);
        WAITV(1);                             // chunk k landed (in-order retirement)
      } else {
        WAITV(0);
      }
      const float* sb = &stg[wave][k & 1][0][0];
      #pragma unroll
      for (int r = 0; r < 8; ++r) {           // uniform row -> broadcast ds_reads
        const float4 a  = *reinterpret_cast<const float4*>(&sb[r * K + i8 * 4]);
        const float4 bv = *reinterpret_cast<const float4*>(&sb[r * K + j8 * 4]);
        OUTER(a, bv);
      }
    }
  }
  for (int q = nch << 3; q < cnt; ++q) {      // tail <= 7 rows: direct uniform loads
    const int r = sIdx[s0 + q];
    const float* rp = mu + (rbase + r) * K;
    const float4 a  = *reinterpret_cast<const float4*>(rp + i8 * 4);
    const float4 bv = *reinterpret_cast<const float4*>(rp + j8 * 4);
    OUTER(a, bv);
  }

  // ---- flush: each group appears once per block -> direct atomics, no LDS reduce ----
  float* raw = ws + RAW_OFF + g * K * K;
  #pragma unroll
  for (int e = 0; e < 16; ++e) {
    const int row = 4 * i8 + (e >> 2), col = 4 * j8 + (e & 3);
    atomicAdd(raw + row * K + col, acc[e]);
  }
  if (i8 == 0) {
    #pragma unroll
    for (int e = 0; e < 4; ++e)
      atomicAdd(ws + MUSUM_OFF + g * K + j8 * 4 + e, ms[e]);
  }
  if (lane == 0) atomicAdd(ws + CNT_OFF + g, (float)cnt);
}

// ---------------- fallback path (B % 1024 != 0): counts + switch-stats ----------------
__global__ __launch_bounds__(256, 8) void gmm_histf(const int* __restrict__ lab,
                                                    float* __restrict__ ws, int B) {
  int c[G];
  #pragma unroll
  for (int g = 0; g < G; ++g) c[g] = 0;
  const int nt = gridDim.x * blockDim.x;
  for (int i = blockIdx.x * blockDim.x + threadIdx.x; i < B; i += nt) {
    const int v = lab[i];
    #pragma unroll
    for (int g = 0; g < G; ++g) c[g] += (v == g) ? 1 : 0;
  }
  const int lane = threadIdx.x & 63;
  #pragma unroll
  for (int g = 0; g < G; ++g) {
    int t = c[g];
    #pragma unroll
    for (int o = 32; o >= 1; o >>= 1) t += __shfl_xor(t, o);
    if (lane == 0) atomicAdd(&ws[CNT_OFF + g], (float)t);
  }
}

#define ACC_CASE(gc_, Av, Bv_) do{ \
  facc[gc_][0]=fmaf(Av.x,Bv_.x,facc[gc_][0]); facc[gc_][1]=fmaf(Av.x,Bv_.y,facc[gc_][1]); \
  facc[gc_][2]=fmaf(Av.y,Bv_.x,facc[gc_][2]); facc[gc_][3]=fmaf(Av.y,Bv_.y,facc[gc_][3]); \
  if (a_blk==0){ msum[gc_][0]+=Bv_.x; msum[gc_][1]+=Bv_.y; } }while(0)
#define PROC(gv, Av, Bv_) switch(gv){ \
  case 0: ACC_CASE(0,Av,Bv_); break; case 1: ACC_CASE(1,Av,Bv_); break; \
  case 2: ACC_CASE(2,Av,Bv_); break; case 3: ACC_CASE(3,Av,Bv_); break; \
  case 4: ACC_CASE(4,Av,Bv_); break; case 5: ACC_CASE(5,Av,Bv_); break; \
  case 6: ACC_CASE(6,Av,Bv_); break; default: ACC_CASE(7,Av,Bv_); break; }

__global__ __launch_bounds__(256, 4) void gmm_stats_fb(const float* __restrict__ mu,
                                                       const int* __restrict__ lab,
                                                       float* __restrict__ ws, int B) {
  const int tid = threadIdx.x;
  const int a_blk = tid >> 4, b_blk = tid & 15;
  const int rpb = (B + 1023) / 1024;
  const long rbase = (long)blockIdx.x * rpb;
  float facc[G][4]; float msum[G][2];
  #pragma unroll
  for (int g = 0; g < G; ++g) { facc[g][0]=facc[g][1]=facc[g][2]=facc[g][3]=0.f; msum[g][0]=msum[g][1]=0.f; }
  const float2* __restrict__ mu2 = reinterpret_cast<const float2*>(mu);
  for (long r = rbase; r < rbase + rpb && r < B; ++r) {
    const float2 Av = mu2[r * 16 + a_blk];
    const float2 Bv_ = mu2[r * 16 + b_blk];
    const int g0 = RF(lab[r]);
    PROC(g0, Av, Bv_);
  }
  const int arow = a_blk * 2, bcol = b_blk * 2;
  #pragma unroll
  for (int g = 0; g < G; ++g) {
    float* base = &ws[RAW_OFF + g * K * K];
    atomicAdd(base + (arow)*K + bcol, facc[g][0]);
    atomicAdd(base + (arow)*K + bcol + 1, facc[g][1]);
    atomicAdd(base + (arow+1)*K + bcol, facc[g][2]);
    atomicAdd(base + (arow+1)*K + bcol + 1, facc[g][3]);
  }
  if (a_blk == 0)
    #pragma unroll
    for (int g = 0; g < G; ++g) {
      atomicAdd(&ws[MUSUM_OFF + g*K + bcol], msum[g][0]);
      atomicAdd(&ws[MUSUM_OFF + g*K + bcol + 1], msum[g][1]);
    }
}

// ---------------- finalize (fp64, validated rounds 2/5-13) ----------------
__global__ __launch_bounds__(512, 1) void gmm_finalize(const float* __restrict__ ws,
                                                       float* __restrict__ out, int B) {
  __shared__ double sig[G][K][K];
  __shared__ double inv[G][K][K];
  __shared__ double mg[G][K];
  __shared__ double ldet[G];
  __shared__ double cshared[G];
  __shared__ double pairsum[G];
  const int tid = threadIdx.x;
  const int w = tid >> 6;
  const int lane = tid & 63;

  if (tid < G) cshared[tid] = (double)ws[CNT_OFF + tid];
  __syncthreads();
  const double cinv = 1.0 / cshared[w];
  if (lane < K) mg[w][lane] = (double)ws[MUSUM_OFF + w * K + lane] * cinv;
  __syncthreads();
  for (int e = lane; e < K * K; e += 64) {
    const int a = e >> 5, b = e & 31;
    double s = (double)ws[RAW_OFF + w * K * K + e] * cinv - mg[w][a] * mg[w][b];
    if (a == b) s += (double)SIGMA_V;
    sig[w][a][b] = s;
  }
  __syncthreads();

  const int c = lane & 31;
  double col[K];
  #pragma unroll
  for (int i2 = 0; i2 < K; ++i2) {
    double sv = sig[w][i2][c];
    col[i2] = (lane < K) ? sv : ((i2 == c) ? 1.0 : 0.0);
  }
  double ld = 0.0;
  #pragma unroll
  for (int j2 = 0; j2 < K; ++j2) {
    double rowj = col[j2];
    double p = __shfl(rowj, j2);
    double pinv = 1.0 / p;
    ld += log(p);
    double scaled = rowj * pinv;
    #pragma unroll
    for (int i2 = 0; i2 < K; ++i2) {
      if (i2 == j2) continue;
      double bij = __shfl(col[i2], j2);
      col[i2] = fma(-bij, scaled, col[i2]);
    }
    col[j2] = scaled;
  }
  if (lane >= K) {
    #pragma unroll
    for (int i2 = 0; i2 < K; ++i2) inv[w][i2][lane - K] = col[i2];
  }
  if (lane == 0) ldet[w] = ld;
  __syncthreads();

  double accp = 0.0;
  for (int jj = 0; jj < G; ++jj) {
    const bool ok = (w < G - 1) && (jj >= 1) && (w != jj);
    if (ok) {
      double t = 0.0;
      for (int e = lane; e < K * K; e += 64) {
        const int a = e >> 5, b = e & 31;
        const double da = mg[jj][a] - mg[w][a];
        const double db = mg[jj][b] - mg[w][b];
        t += inv[jj][a][b] * (sig[w][a][b] + da * db);
      }
      #pragma unroll
      for (int off = 32; off >= 1; off >>= 1) t += __shfl_xor(t, off);
      if (lane == 0) accp += 0.5 * (t - (double)K + ldet[jj] - ldet[w]) * cshared[w] * cshared[jj];
    }
  }
  if (lane == 0) pairsum[w] = accp;
  __syncthreads();
  if (tid == 0) {
    double tot = 0.0;
    #pragma unroll
    for (int q = 0; q < G; ++q) tot += pairsum[q];
    const double Bf = (double)B;
    out[0] = (float)(tot / (Bf * Bf));
  }
}

extern "C" void kernel_launch(void* const* d_in, const int* in_sizes, int n_in,
                              void* d_out, int out_size, void* d_ws, size_t ws_size,
                              hipStream_t stream) {
  const float* mu = (const float*)d_in[0];
  const int* lab = (const int*)d_in[1];
  float* ws = (float*)d_ws;
  float* out = (float*)d_out;
  const int B = in_sizes[1];

  hipMemsetAsync(d_ws, 0, (size_t)WS_FLOATS * 4, stream);

  if ((B % REG) == 0) {
    hipLaunchKernelGGL(gmm_all, dim3(B / REG), dim3(512), 0, stream, mu, lab, ws);
  } else {
    hipLaunchKernelGGL(gmm_histf, dim3(256), dim3(256), 0, stream, lab, ws, B);
    hipLaunchKernelGGL(gmm_stats_fb, dim3(1024), dim3(256), 0, stream, mu, lab, ws, B);
  }
  hipLaunchKernelGGL(gmm_finalize, dim3(1), dim3(512), 0, stream, ws, out, B);
}